// Round 1
// baseline (262.700 us; speedup 1.0000x reference)
//
#include <hip/hip_runtime.h>
#include <cstdint>
#include <cstddef>

#define BB   32
#define NN   1024
#define FIN  128
#define FOUT 128

typedef __attribute__((ext_vector_type(8))) short bf16x8;
typedef __attribute__((ext_vector_type(4))) float f32x4;

__device__ __forceinline__ unsigned int f2bf(float f) {
    union { float f; unsigned int u; } v; v.f = f;
    unsigned int u = v.u;
    return (u + 0x7FFFu + ((u >> 16) & 1u)) >> 16;   // RNE fp32 -> bf16
}
__device__ __forceinline__ unsigned int pack2(float a, float b) {
    return f2bf(a) | (f2bf(b) << 16);
}

// ---------------------------------------------------------------------------
// Kernel 1: Yt[b][o][m] = sum_f node[b][m][f] * W[o][f]   (bf16 output, B^T
// layout so kernel 2's B-fragment reads are k-contiguous)
// grid 512 = 32 batches x 16 m-tiles of 64; block 256 (4 waves, 2x2 of 32x64)
// ---------------------------------------------------------------------------
__global__ __launch_bounds__(256) void y_kernel(const float* __restrict__ node,
                                                const float* __restrict__ W,
                                                unsigned short* __restrict__ Yt) {
    __shared__ unsigned short Alds[64 * 136];    // node tile [m][f], pad 136
    __shared__ unsigned short Blds[128 * 136];   // W [o][f] (already B^T form)

    const int tid = threadIdx.x;
    const int bid = blockIdx.x;
    const int b   = bid >> 4;
    const int m0  = (bid & 15) * 64;

    // stage node tile [64][128] fp32 -> bf16 LDS
    {
        const int r  = tid >> 2;
        const int c0 = (tid & 3) * 32;
        const float* src = node + ((size_t)b * NN + m0 + r) * FIN + c0;
        float4 v[8];
        #pragma unroll
        for (int j = 0; j < 8; ++j) v[j] = ((const float4*)src)[j];
        #pragma unroll
        for (int j = 0; j < 4; ++j) {
            uint4 p;
            p.x = pack2(v[2*j].x,   v[2*j].y);
            p.y = pack2(v[2*j].z,   v[2*j].w);
            p.z = pack2(v[2*j+1].x, v[2*j+1].y);
            p.w = pack2(v[2*j+1].z, v[2*j+1].w);
            *(uint4*)&Alds[r * 136 + c0 + j * 8] = p;
        }
    }
    // stage W [128][128] fp32 -> bf16 LDS
    {
        const int r  = tid >> 1;
        const int c0 = (tid & 1) * 64;
        const float* src = W + r * FIN + c0;
        #pragma unroll
        for (int j = 0; j < 8; ++j) {
            float4 v0 = ((const float4*)src)[2*j];
            float4 v1 = ((const float4*)src)[2*j + 1];
            uint4 p;
            p.x = pack2(v0.x, v0.y);
            p.y = pack2(v0.z, v0.w);
            p.z = pack2(v1.x, v1.y);
            p.w = pack2(v1.z, v1.w);
            *(uint4*)&Blds[r * 136 + c0 + j * 8] = p;
        }
    }
    __syncthreads();

    const int w = tid >> 6, lane = tid & 63;
    const int wm = (w & 1) * 32, wn = (w >> 1) * 64;
    const int lcol = lane & 15, lk = (lane >> 4) * 8;

    f32x4 acc[2][4] = {};
    #pragma unroll
    for (int kc = 0; kc < 4; ++kc) {
        const int kof = kc * 32 + lk;
        bf16x8 a[2], bb[4];
        #pragma unroll
        for (int mi = 0; mi < 2; ++mi)
            a[mi] = *(const bf16x8*)&Alds[(wm + mi*16 + lcol) * 136 + kof];
        #pragma unroll
        for (int ni = 0; ni < 4; ++ni)
            bb[ni] = *(const bf16x8*)&Blds[(wn + ni*16 + lcol) * 136 + kof];
        #pragma unroll
        for (int mi = 0; mi < 2; ++mi)
            #pragma unroll
            for (int ni = 0; ni < 4; ++ni)
                acc[mi][ni] = __builtin_amdgcn_mfma_f32_16x16x32_bf16(
                    a[mi], bb[ni], acc[mi][ni], 0, 0, 0);
    }
    __syncthreads();   // everyone done reading Blds before aliasing it

    // transpose via LDS: Clds[o][m], stride 72 (C/D frag: col=lane&15,
    // row=(lane>>4)*4+reg -> the 4 regs are consecutive m -> pack uint2)
    unsigned short* Clds = Blds;
    const int rq = (lane >> 4) * 4;
    #pragma unroll
    for (int mi = 0; mi < 2; ++mi) {
        const int mloc = wm + mi * 16 + rq;
        #pragma unroll
        for (int ni = 0; ni < 4; ++ni) {
            const int o = wn + ni * 16 + lcol;
            uint2 p;
            p.x = pack2(acc[mi][ni][0], acc[mi][ni][1]);
            p.y = pack2(acc[mi][ni][2], acc[mi][ni][3]);
            *(uint2*)&Clds[o * 72 + mloc] = p;
        }
    }
    __syncthreads();

    // coalesced store: thread t writes 32 bf16 of row o
    {
        const int o = tid >> 1, half = tid & 1;
        unsigned short* dst = Yt + ((size_t)b * FOUT + o) * NN + m0 + half * 32;
        const unsigned short* s = &Clds[o * 72 + half * 32];
        #pragma unroll
        for (int j = 0; j < 8; ++j) ((uint2*)dst)[j] = ((const uint2*)s)[j];
    }
}

// ---------------------------------------------------------------------------
// Kernel 2: out[b][n][o] = leaky( (sum_m adj[b][n][m]*Yt[b][o][m]) / rowsum
//                                  + bias[o] )
// grid 512 (2 blocks/CU); block 256; tile 64 n-rows x 128 o-cols; BK=64,
// 16 K-steps; register prefetch pipeline; rowsum fused into A staging.
// ---------------------------------------------------------------------------
__global__ __launch_bounds__(256) void gcn_kernel(const float* __restrict__ adj,
                                                  const unsigned short* __restrict__ Yt,
                                                  const float* __restrict__ bias,
                                                  float* __restrict__ out) {
    __shared__ unsigned short Alds[64 * 72];    // adj tile [n][k] bf16, pad 72
    __shared__ unsigned short Blds[128 * 72];   // Yt tile [o][k] bf16
    __shared__ float rs[64];

    const int tid = threadIdx.x;
    const int bid = blockIdx.x;
    const int b   = bid >> 4;
    const int n0  = (bid & 15) * 64;

    const int ar  = tid >> 2;            // adj row (fixed per thread)
    const int ac0 = (tid & 3) * 16;      // k-offset within BK
    const int br  = tid >> 1;            // Yt row (o)
    const int bc0 = (tid & 1) * 32;

    const float*          aptr = adj + ((size_t)b * NN + n0 + ar) * NN + ac0;
    const unsigned short* bptr = Yt  + ((size_t)b * FOUT + br) * NN + bc0;

    float rsum = 0.f;
    float4 av[4];
    uint4  bv[4];
    #pragma unroll
    for (int j = 0; j < 4; ++j) av[j] = ((const float4*)aptr)[j];
    #pragma unroll
    for (int j = 0; j < 4; ++j) bv[j] = ((const uint4*)bptr)[j];

    const int w = tid >> 6, lane = tid & 63;
    const int wm = (w & 1) * 32, wn = (w >> 1) * 64;
    const int lcol = lane & 15, lk = (lane >> 4) * 8;

    f32x4 acc[2][4] = {};

    for (int s = 0; s < 16; ++s) {
        // drain prefetched regs into LDS (fp32->bf16 for A, fused rowsum)
        #pragma unroll
        for (int j = 0; j < 4; ++j) {
            float4 v = av[j];
            rsum += (v.x + v.y) + (v.z + v.w);
            uint2 p;
            p.x = pack2(v.x, v.y);
            p.y = pack2(v.z, v.w);
            *(uint2*)&Alds[ar * 72 + ac0 + j * 4] = p;
        }
        #pragma unroll
        for (int j = 0; j < 4; ++j)
            *(uint4*)&Blds[br * 72 + bc0 + j * 8] = bv[j];

        // issue next step's global loads before the barrier -> overlap MFMA
        if (s < 15) {
            const float*          ap = aptr + (s + 1) * 64;
            const unsigned short* bp = bptr + (s + 1) * 64;
            #pragma unroll
            for (int j = 0; j < 4; ++j) av[j] = ((const float4*)ap)[j];
            #pragma unroll
            for (int j = 0; j < 4; ++j) bv[j] = ((const uint4*)bp)[j];
        }
        __syncthreads();

        #pragma unroll
        for (int kc = 0; kc < 2; ++kc) {
            const int kof = kc * 32 + lk;
            bf16x8 af[2], bf_[4];
            #pragma unroll
            for (int mi = 0; mi < 2; ++mi)
                af[mi] = *(const bf16x8*)&Alds[(wm + mi*16 + lcol) * 72 + kof];
            #pragma unroll
            for (int ni = 0; ni < 4; ++ni)
                bf_[ni] = *(const bf16x8*)&Blds[(wn + ni*16 + lcol) * 72 + kof];
            #pragma unroll
            for (int mi = 0; mi < 2; ++mi)
                #pragma unroll
                for (int ni = 0; ni < 4; ++ni)
                    acc[mi][ni] = __builtin_amdgcn_mfma_f32_16x16x32_bf16(
                        af[mi], bf_[ni], acc[mi][ni], 0, 0, 0);
        }
        __syncthreads();
    }

    // rowsum: 4 consecutive lanes share a row
    rsum += __shfl_xor(rsum, 1);
    rsum += __shfl_xor(rsum, 2);
    if ((tid & 3) == 0) rs[ar] = rsum;
    __syncthreads();

    const int rq = (lane >> 4) * 4;
    float* outB = out + ((size_t)b * NN + n0) * FOUT;
    float bcol[4];
    #pragma unroll
    for (int ni = 0; ni < 4; ++ni) bcol[ni] = bias[wn + ni * 16 + lcol];

    #pragma unroll
    for (int mi = 0; mi < 2; ++mi) {
        const int rbase = wm + mi * 16 + rq;
        float sc[4];
        #pragma unroll
        for (int j = 0; j < 4; ++j) sc[j] = 1.0f / rs[rbase + j];
        #pragma unroll
        for (int ni = 0; ni < 4; ++ni) {
            const int col = wn + ni * 16 + lcol;
            #pragma unroll
            for (int j = 0; j < 4; ++j) {
                float v = acc[mi][ni][j] * sc[j] + bcol[ni];
                v = (v >= 0.f) ? v : 0.01f * v;
                outB[(size_t)(rbase + j) * FOUT + col] = v;
            }
        }
    }
}

extern "C" void kernel_launch(void* const* d_in, const int* in_sizes, int n_in,
                              void* d_out, int out_size, void* d_ws, size_t ws_size,
                              hipStream_t stream) {
    const float* node = (const float*)d_in[0];   // [32,1024,128]
    const float* adj  = (const float*)d_in[1];   // [32,1024,1024]
    const float* W    = (const float*)d_in[2];   // [128,128]
    const float* bias = (const float*)d_in[3];   // [128]
    float* out = (float*)d_out;                  // [32,1024,128] fp32
    unsigned short* Yt = (unsigned short*)d_ws;  // [32,128,1024] bf16 = 8 MiB

    hipLaunchKernelGGL(y_kernel,   dim3(512), dim3(256), 0, stream, node, W, Yt);
    hipLaunchKernelGGL(gcn_kernel, dim3(512), dim3(256), 0, stream, adj, Yt, bias, out);
}